// Round 1
// baseline (118.290 us; speedup 1.0000x reference)
//
#include <hip/hip_runtime.h>

// Problem constants (fixed by setup_inputs)
#define Q 200
#define KTOP 100
#define HW 640000          // 800*800
#define HW4 160000         // HW/4 float4s per row
#define CHUNKS 40          // blocks per row in mask kernel
#define OUT_MASK 0
#define OUT_SCORES 64000000
#define OUT_LABELS 64000100
#define OUT_IDS    64000200
#define OUT_VALID  64000300

// ws layout (in 4-byte elements):
// [0,128)           int   topk_idx
// [128,256)         float topk_score
// [256,256+4000)    float partial_sig [100][40]
// [4256,8256)       float partial_cnt [100][40]

__global__ void topk_kernel(const float* __restrict__ logits,
                            int* __restrict__ ws_idx,
                            float* __restrict__ ws_sc) {
    __shared__ float s[Q];
    int t = threadIdx.x;
    if (t < Q) {
        float l0 = logits[2 * t + 0];
        float l1 = logits[2 * t + 1];
        float m = fmaxf(l0, l1);
        float e0 = expf(l0 - m);   // precise expf: match numpy softmax ordering
        float e1 = expf(l1 - m);
        s[t] = e0 / (e0 + e1);     // softmax prob of class 0 (drop no-object col)
    }
    __syncthreads();
    if (t < Q) {
        float v = s[t];
        int rank = 0;
        for (int j = 0; j < Q; ++j) {
            float sj = s[j];
            // stable descending sort rank (matches jax.lax.top_k tie-breaking)
            rank += (sj > v) || (sj == v && j < t);
        }
        if (rank < KTOP) {
            ws_idx[rank] = t;
            ws_sc[rank] = v;
        }
    }
}

__global__ __launch_bounds__(256) void mask_kernel(
        const float4* __restrict__ pm,
        const int* __restrict__ ws_idx,
        float4* __restrict__ out,
        float* __restrict__ psig,
        float* __restrict__ pcnt) {
    const int row = blockIdx.y;              // 0..99
    const int q = ws_idx[row];               // gathered query index
    const float4* __restrict__ src = pm + (size_t)q * HW4;
    float4* __restrict__ dst = out + (size_t)row * HW4;

    float sumsig = 0.f;
    float cnt = 0.f;
    const int stride = gridDim.x * blockDim.x;   // 40*256 = 10240
    for (int i = blockIdx.x * blockDim.x + threadIdx.x; i < HW4; i += stride) {
        float4 v = src[i];
        float4 b;
        b.x = v.x > 0.f ? 1.f : 0.f;
        b.y = v.y > 0.f ? 1.f : 0.f;
        b.z = v.z > 0.f ? 1.f : 0.f;
        b.w = v.w > 0.f ? 1.f : 0.f;
        dst[i] = b;
        // sigmoid only contributes where mask is positive
        sumsig += b.x * __fdividef(1.f, 1.f + __expf(-v.x));
        sumsig += b.y * __fdividef(1.f, 1.f + __expf(-v.y));
        sumsig += b.z * __fdividef(1.f, 1.f + __expf(-v.z));
        sumsig += b.w * __fdividef(1.f, 1.f + __expf(-v.w));
        cnt += b.x + b.y + b.z + b.w;
    }

    // wave (64-lane) reduction
    for (int off = 32; off > 0; off >>= 1) {
        sumsig += __shfl_down(sumsig, off);
        cnt    += __shfl_down(cnt, off);
    }
    __shared__ float ls[4], lc[4];
    int wid = threadIdx.x >> 6;
    int lane = threadIdx.x & 63;
    if (lane == 0) { ls[wid] = sumsig; lc[wid] = cnt; }
    __syncthreads();
    if (threadIdx.x == 0) {
        float S = ls[0] + ls[1] + ls[2] + ls[3];
        float C = lc[0] + lc[1] + lc[2] + lc[3];
        psig[row * CHUNKS + blockIdx.x] = S;
        pcnt[row * CHUNKS + blockIdx.x] = C;
    }
}

__global__ void final_kernel(const int* __restrict__ ws_idx,
                             const float* __restrict__ ws_sc,
                             const float* __restrict__ psig,
                             const float* __restrict__ pcnt,
                             const int* __restrict__ labels,
                             const int* __restrict__ ids,
                             float* __restrict__ out) {
    int t = threadIdx.x;
    if (t < KTOP) {
        float S = 0.f, C = 0.f;
        for (int j = 0; j < CHUNKS; ++j) {
            S += psig[t * CHUNKS + j];
            C += pcnt[t * CHUNKS + j];
        }
        float ms = S / (C + 1e-6f);
        int q = ws_idx[t];
        out[OUT_SCORES + t] = ws_sc[t] * ms;
        out[OUT_LABELS + t] = (float)labels[q];
        out[OUT_IDS + t]    = (float)ids[q];
        out[OUT_VALID + t]  = 1.0f;   // threshold = -1e9 -> all valid
    }
}

extern "C" void kernel_launch(void* const* d_in, const int* in_sizes, int n_in,
                              void* d_out, int out_size, void* d_ws, size_t ws_size,
                              hipStream_t stream) {
    const float* pred_masks  = (const float*)d_in[0];
    const float* pred_logits = (const float*)d_in[1];
    const int*   labels      = (const int*)d_in[2];
    const int*   ids         = (const int*)d_in[3];
    float* out = (float*)d_out;

    int*   ws_idx = (int*)d_ws;
    float* ws_sc  = (float*)d_ws + 128;
    float* psig   = (float*)d_ws + 256;
    float* pcnt   = psig + KTOP * CHUNKS;

    topk_kernel<<<1, 256, 0, stream>>>(pred_logits, ws_idx, ws_sc);

    dim3 grid(CHUNKS, KTOP);
    mask_kernel<<<grid, 256, 0, stream>>>((const float4*)pred_masks, ws_idx,
                                          (float4*)out, psig, pcnt);

    final_kernel<<<1, 128, 0, stream>>>(ws_idx, ws_sc, psig, pcnt,
                                        labels, ids, out);
}

// Round 2
// 105.174 us; speedup vs baseline: 1.1247x; 1.1247x over previous
//
#include <hip/hip_runtime.h>

// Problem constants (fixed by setup_inputs)
#define Q 200
#define KTOP 100
#define HW 640000          // 800*800
#define HW4 160000         // HW/4 float4s per row
#define CHUNKS 125         // blocks per row; 160000/(125*256) = 5 exact iters
#define ITERS 5
#define CHUNK4 1280        // float4s per block chunk (256*5)
#define OUT_SCORES 64000000
#define OUT_LABELS 64000100
#define OUT_IDS    64000200
#define OUT_VALID  64000300

typedef float vfloat4 __attribute__((ext_vector_type(4)));

// ws layout (4-byte elements):
// [0,128)               int   topk_idx
// [128,256)             float topk_score
// [256,256+12500)       float partial_sig [100][125]
// [12756,25256)         float partial_cnt [100][125]

__global__ void topk_kernel(const float* __restrict__ logits,
                            int* __restrict__ ws_idx,
                            float* __restrict__ ws_sc) {
    __shared__ float s[Q];
    int t = threadIdx.x;
    if (t < Q) {
        float l0 = logits[2 * t + 0];
        float l1 = logits[2 * t + 1];
        float m = fmaxf(l0, l1);
        float e0 = expf(l0 - m);   // precise expf: match numpy softmax ordering
        float e1 = expf(l1 - m);
        s[t] = e0 / (e0 + e1);     // softmax prob of class 0 (drop no-object col)
    }
    __syncthreads();
    if (t < Q) {
        float v = s[t];
        int rank = 0;
        for (int j = 0; j < Q; ++j) {
            float sj = s[j];
            // stable descending rank (matches jax.lax.top_k tie-breaking)
            rank += (sj > v) || (sj == v && j < t);
        }
        if (rank < KTOP) {
            ws_idx[rank] = t;
            ws_sc[rank] = v;
        }
    }
}

__global__ __launch_bounds__(256) void mask_kernel(
        const vfloat4* __restrict__ pm,
        const int* __restrict__ ws_idx,
        vfloat4* __restrict__ out,
        float* __restrict__ psig,
        float* __restrict__ pcnt) {
    const int row = blockIdx.y;              // 0..99
    const int q = ws_idx[row];               // gathered query index
    const vfloat4* __restrict__ src = pm + (size_t)q * HW4
                                         + (size_t)blockIdx.x * CHUNK4 + threadIdx.x;
    vfloat4* __restrict__ dst = out + (size_t)row * HW4
                                    + (size_t)blockIdx.x * CHUNK4 + threadIdx.x;

    float sumsig = 0.f;
    float cnt = 0.f;
#pragma unroll
    for (int it = 0; it < ITERS; ++it) {
        vfloat4 v = __builtin_nontemporal_load(src + it * 256);
        vfloat4 b;
        b.x = v.x > 0.f ? 1.f : 0.f;
        b.y = v.y > 0.f ? 1.f : 0.f;
        b.z = v.z > 0.f ? 1.f : 0.f;
        b.w = v.w > 0.f ? 1.f : 0.f;
        __builtin_nontemporal_store(b, dst + it * 256);
        sumsig += b.x * __fdividef(1.f, 1.f + __expf(-v.x));
        sumsig += b.y * __fdividef(1.f, 1.f + __expf(-v.y));
        sumsig += b.z * __fdividef(1.f, 1.f + __expf(-v.z));
        sumsig += b.w * __fdividef(1.f, 1.f + __expf(-v.w));
        cnt += b.x + b.y + b.z + b.w;
    }

    // wave (64-lane) reduction
    for (int off = 32; off > 0; off >>= 1) {
        sumsig += __shfl_down(sumsig, off);
        cnt    += __shfl_down(cnt, off);
    }
    __shared__ float ls[4], lc[4];
    int wid = threadIdx.x >> 6;
    int lane = threadIdx.x & 63;
    if (lane == 0) { ls[wid] = sumsig; lc[wid] = cnt; }
    __syncthreads();
    if (threadIdx.x == 0) {
        float S = ls[0] + ls[1] + ls[2] + ls[3];
        float C = lc[0] + lc[1] + lc[2] + lc[3];
        psig[row * CHUNKS + blockIdx.x] = S;
        pcnt[row * CHUNKS + blockIdx.x] = C;
    }
}

__global__ void final_kernel(const int* __restrict__ ws_idx,
                             const float* __restrict__ ws_sc,
                             const float* __restrict__ psig,
                             const float* __restrict__ pcnt,
                             const int* __restrict__ labels,
                             const int* __restrict__ ids,
                             float* __restrict__ out) {
    int t = threadIdx.x;
    if (t < KTOP) {
        float S = 0.f, C = 0.f;
        for (int j = 0; j < CHUNKS; ++j) {
            S += psig[t * CHUNKS + j];
            C += pcnt[t * CHUNKS + j];
        }
        float ms = S / (C + 1e-6f);
        int q = ws_idx[t];
        out[OUT_SCORES + t] = ws_sc[t] * ms;
        out[OUT_LABELS + t] = (float)labels[q];
        out[OUT_IDS + t]    = (float)ids[q];
        out[OUT_VALID + t]  = 1.0f;   // threshold = -1e9 -> all valid
    }
}

extern "C" void kernel_launch(void* const* d_in, const int* in_sizes, int n_in,
                              void* d_out, int out_size, void* d_ws, size_t ws_size,
                              hipStream_t stream) {
    const float* pred_masks  = (const float*)d_in[0];
    const float* pred_logits = (const float*)d_in[1];
    const int*   labels      = (const int*)d_in[2];
    const int*   ids         = (const int*)d_in[3];
    float* out = (float*)d_out;

    int*   ws_idx = (int*)d_ws;
    float* ws_sc  = (float*)d_ws + 128;
    float* psig   = (float*)d_ws + 256;
    float* pcnt   = psig + KTOP * CHUNKS;

    topk_kernel<<<1, 256, 0, stream>>>(pred_logits, ws_idx, ws_sc);

    dim3 grid(CHUNKS, KTOP);
    mask_kernel<<<grid, 256, 0, stream>>>((const vfloat4*)pred_masks, ws_idx,
                                          (vfloat4*)out, psig, pcnt);

    final_kernel<<<1, 128, 0, stream>>>(ws_idx, ws_sc, psig, pcnt,
                                        labels, ids, out);
}

// Round 3
// 98.109 us; speedup vs baseline: 1.2057x; 1.0720x over previous
//
#include <hip/hip_runtime.h>

// Problem constants (fixed by setup_inputs)
#define Q 200
#define KTOP 100
#define HW 640000          // 800*800
#define HW4 160000         // HW/4 float4s per row
#define CHUNKS 125         // blocks per row; 160000/(125*256) = 5 exact iters
#define ITERS 5
#define CHUNK4 1280        // float4s per block chunk (256*5)
#define OUT_SCORES 64000000
#define OUT_LABELS 64000100
#define OUT_IDS    64000200
#define OUT_VALID  64000300

typedef float vfloat4 __attribute__((ext_vector_type(4)));

// ws layout (4-byte elements):
// [0,128)               int   topk_idx
// [128,256)             float topk_score
// [256,256+12500)       float partial_sig [100][125]
// [12756,25256)         float partial_cnt [100][125]

__global__ void topk_kernel(const float* __restrict__ logits,
                            int* __restrict__ ws_idx,
                            float* __restrict__ ws_sc) {
    __shared__ float s[Q];
    int t = threadIdx.x;
    if (t < Q) {
        float l0 = logits[2 * t + 0];
        float l1 = logits[2 * t + 1];
        float m = fmaxf(l0, l1);
        float e0 = expf(l0 - m);   // precise expf: match numpy softmax ordering
        float e1 = expf(l1 - m);
        s[t] = e0 / (e0 + e1);     // softmax prob of class 0 (drop no-object col)
    }
    __syncthreads();
    if (t < Q) {
        float v = s[t];
        int rank = 0;
        for (int j = 0; j < Q; ++j) {
            float sj = s[j];
            // stable descending rank (matches jax.lax.top_k tie-breaking)
            rank += (sj > v) || (sj == v && j < t);
        }
        if (rank < KTOP) {
            ws_idx[rank] = t;
            ws_sc[rank] = v;
        }
    }
}

__global__ __launch_bounds__(256) void mask_kernel(
        const vfloat4* __restrict__ pm,
        const int* __restrict__ ws_idx,
        vfloat4* __restrict__ out,
        float* __restrict__ psig,
        float* __restrict__ pcnt) {
    const int row = blockIdx.y;              // 0..99
    const int q = ws_idx[row];               // gathered query index
    const vfloat4* __restrict__ src = pm + (size_t)q * HW4
                                         + (size_t)blockIdx.x * CHUNK4 + threadIdx.x;
    vfloat4* __restrict__ dst = out + (size_t)row * HW4
                                    + (size_t)blockIdx.x * CHUNK4 + threadIdx.x;

    // 4 independent accumulator lanes to break the serial dependency chain
    float s0 = 0.f, s1 = 0.f, s2 = 0.f, s3 = 0.f;
    float c0 = 0.f, c1 = 0.f, c2 = 0.f, c3 = 0.f;
#pragma unroll
    for (int it = 0; it < ITERS; ++it) {
        vfloat4 v = __builtin_nontemporal_load(src + it * 256);  // dead stream: keep out of L2
        vfloat4 b;
        b.x = v.x > 0.f ? 1.f : 0.f;
        b.y = v.y > 0.f ? 1.f : 0.f;
        b.z = v.z > 0.f ? 1.f : 0.f;
        b.w = v.w > 0.f ? 1.f : 0.f;
        dst[it * 256] = b;   // normal cached store (full-line coverage, no RFO; nt stores were slower path)
        s0 += b.x * __fdividef(1.f, 1.f + __expf(-v.x));
        s1 += b.y * __fdividef(1.f, 1.f + __expf(-v.y));
        s2 += b.z * __fdividef(1.f, 1.f + __expf(-v.z));
        s3 += b.w * __fdividef(1.f, 1.f + __expf(-v.w));
        c0 += b.x; c1 += b.y; c2 += b.z; c3 += b.w;
    }
    float sumsig = (s0 + s1) + (s2 + s3);
    float cnt    = (c0 + c1) + (c2 + c3);

    // wave (64-lane) reduction
    for (int off = 32; off > 0; off >>= 1) {
        sumsig += __shfl_down(sumsig, off);
        cnt    += __shfl_down(cnt, off);
    }
    __shared__ float ls[4], lc[4];
    int wid = threadIdx.x >> 6;
    int lane = threadIdx.x & 63;
    if (lane == 0) { ls[wid] = sumsig; lc[wid] = cnt; }
    __syncthreads();
    if (threadIdx.x == 0) {
        float S = ls[0] + ls[1] + ls[2] + ls[3];
        float C = lc[0] + lc[1] + lc[2] + lc[3];
        psig[row * CHUNKS + blockIdx.x] = S;
        pcnt[row * CHUNKS + blockIdx.x] = C;
    }
}

__global__ void final_kernel(const int* __restrict__ ws_idx,
                             const float* __restrict__ ws_sc,
                             const float* __restrict__ psig,
                             const float* __restrict__ pcnt,
                             const int* __restrict__ labels,
                             const int* __restrict__ ids,
                             float* __restrict__ out) {
    int t = threadIdx.x;
    if (t < KTOP) {
        float S = 0.f, C = 0.f;
        for (int j = 0; j < CHUNKS; ++j) {
            S += psig[t * CHUNKS + j];
            C += pcnt[t * CHUNKS + j];
        }
        float ms = S / (C + 1e-6f);
        int q = ws_idx[t];
        out[OUT_SCORES + t] = ws_sc[t] * ms;
        out[OUT_LABELS + t] = (float)labels[q];
        out[OUT_IDS + t]    = (float)ids[q];
        out[OUT_VALID + t]  = 1.0f;   // threshold = -1e9 -> all valid
    }
}

extern "C" void kernel_launch(void* const* d_in, const int* in_sizes, int n_in,
                              void* d_out, int out_size, void* d_ws, size_t ws_size,
                              hipStream_t stream) {
    const float* pred_masks  = (const float*)d_in[0];
    const float* pred_logits = (const float*)d_in[1];
    const int*   labels      = (const int*)d_in[2];
    const int*   ids         = (const int*)d_in[3];
    float* out = (float*)d_out;

    int*   ws_idx = (int*)d_ws;
    float* ws_sc  = (float*)d_ws + 128;
    float* psig   = (float*)d_ws + 256;
    float* pcnt   = psig + KTOP * CHUNKS;

    topk_kernel<<<1, 256, 0, stream>>>(pred_logits, ws_idx, ws_sc);

    dim3 grid(CHUNKS, KTOP);
    mask_kernel<<<grid, 256, 0, stream>>>((const vfloat4*)pred_masks, ws_idx,
                                          (vfloat4*)out, psig, pcnt);

    final_kernel<<<1, 128, 0, stream>>>(ws_idx, ws_sc, psig, pcnt,
                                        labels, ids, out);
}

// Round 4
// 97.530 us; speedup vs baseline: 1.2129x; 1.0059x over previous
//
#include <hip/hip_runtime.h>

// Problem constants (fixed by setup_inputs)
#define Q 200
#define KTOP 100
#define HW 640000          // 800*800
#define HW4 160000         // HW/4 float4s per row
#define CHUNKS 125         // blocks per row; 160000/(125*256) = 5 exact iters
#define ITERS 5
#define CHUNK4 1280        // float4s per block chunk (256*5)
#define OUT_SCORES 64000000
#define OUT_LABELS 64000100
#define OUT_IDS    64000200
#define OUT_VALID  64000300

typedef float vfloat4 __attribute__((ext_vector_type(4)));

// ws layout (4-byte elements):
// [0,128)               int   topk_idx
// [128,256)             float topk_score
// [256,256+12500)       float partial_sig [100][125]
// [12756,25256)         float partial_cnt [100][125]

__global__ void topk_kernel(const float* __restrict__ logits,
                            int* __restrict__ ws_idx,
                            float* __restrict__ ws_sc) {
    __shared__ float s[Q];
    int t = threadIdx.x;
    if (t < Q) {
        float l0 = logits[2 * t + 0];
        float l1 = logits[2 * t + 1];
        float m = fmaxf(l0, l1);
        float e0 = expf(l0 - m);   // precise expf: match numpy softmax ordering
        float e1 = expf(l1 - m);
        s[t] = e0 / (e0 + e1);     // softmax prob of class 0 (drop no-object col)
    }
    __syncthreads();
    if (t < Q) {
        float v = s[t];
        int rank = 0;
        for (int j = 0; j < Q; ++j) {
            float sj = s[j];
            // stable descending rank (matches jax.lax.top_k tie-breaking)
            rank += (sj > v) || (sj == v && j < t);
        }
        if (rank < KTOP) {
            ws_idx[rank] = t;
            ws_sc[rank] = v;
        }
    }
}

__global__ __launch_bounds__(256) void mask_kernel(
        const vfloat4* __restrict__ pm,
        const int* __restrict__ ws_idx,
        vfloat4* __restrict__ out,
        float* __restrict__ psig,
        float* __restrict__ pcnt) {
    const int row = blockIdx.y;              // 0..99
    const int q = ws_idx[row];               // gathered query index
    const vfloat4* __restrict__ src = pm + (size_t)q * HW4
                                         + (size_t)blockIdx.x * CHUNK4 + threadIdx.x;
    vfloat4* __restrict__ dst = out + (size_t)row * HW4
                                    + (size_t)blockIdx.x * CHUNK4 + threadIdx.x;

    // 4 independent accumulator lanes to break the serial dependency chain
    float s0 = 0.f, s1 = 0.f, s2 = 0.f, s3 = 0.f;
    float c0 = 0.f, c1 = 0.f, c2 = 0.f, c3 = 0.f;
#pragma unroll
    for (int it = 0; it < ITERS; ++it) {
        // temporal load: read set (256 MB = L3 size) should stay MALL-resident
        // across graph replays
        vfloat4 v = src[it * 256];
        vfloat4 b;
        b.x = v.x > 0.f ? 1.f : 0.f;
        b.y = v.y > 0.f ? 1.f : 0.f;
        b.z = v.z > 0.f ? 1.f : 0.f;
        b.w = v.w > 0.f ? 1.f : 0.f;
        // nontemporal store: dead write stream, don't evict the read set from L3
        __builtin_nontemporal_store(b, dst + it * 256);
        s0 += b.x * __fdividef(1.f, 1.f + __expf(-v.x));
        s1 += b.y * __fdividef(1.f, 1.f + __expf(-v.y));
        s2 += b.z * __fdividef(1.f, 1.f + __expf(-v.z));
        s3 += b.w * __fdividef(1.f, 1.f + __expf(-v.w));
        c0 += b.x; c1 += b.y; c2 += b.z; c3 += b.w;
    }
    float sumsig = (s0 + s1) + (s2 + s3);
    float cnt    = (c0 + c1) + (c2 + c3);

    // wave (64-lane) reduction
    for (int off = 32; off > 0; off >>= 1) {
        sumsig += __shfl_down(sumsig, off);
        cnt    += __shfl_down(cnt, off);
    }
    __shared__ float ls[4], lc[4];
    int wid = threadIdx.x >> 6;
    int lane = threadIdx.x & 63;
    if (lane == 0) { ls[wid] = sumsig; lc[wid] = cnt; }
    __syncthreads();
    if (threadIdx.x == 0) {
        float S = ls[0] + ls[1] + ls[2] + ls[3];
        float C = lc[0] + lc[1] + lc[2] + lc[3];
        psig[row * CHUNKS + blockIdx.x] = S;
        pcnt[row * CHUNKS + blockIdx.x] = C;
    }
}

__global__ void final_kernel(const int* __restrict__ ws_idx,
                             const float* __restrict__ ws_sc,
                             const float* __restrict__ psig,
                             const float* __restrict__ pcnt,
                             const int* __restrict__ labels,
                             const int* __restrict__ ids,
                             float* __restrict__ out) {
    int t = threadIdx.x;
    if (t < KTOP) {
        float S = 0.f, C = 0.f;
        for (int j = 0; j < CHUNKS; ++j) {
            S += psig[t * CHUNKS + j];
            C += pcnt[t * CHUNKS + j];
        }
        float ms = S / (C + 1e-6f);
        int q = ws_idx[t];
        out[OUT_SCORES + t] = ws_sc[t] * ms;
        out[OUT_LABELS + t] = (float)labels[q];
        out[OUT_IDS + t]    = (float)ids[q];
        out[OUT_VALID + t]  = 1.0f;   // threshold = -1e9 -> all valid
    }
}

extern "C" void kernel_launch(void* const* d_in, const int* in_sizes, int n_in,
                              void* d_out, int out_size, void* d_ws, size_t ws_size,
                              hipStream_t stream) {
    const float* pred_masks  = (const float*)d_in[0];
    const float* pred_logits = (const float*)d_in[1];
    const int*   labels      = (const int*)d_in[2];
    const int*   ids         = (const int*)d_in[3];
    float* out = (float*)d_out;

    int*   ws_idx = (int*)d_ws;
    float* ws_sc  = (float*)d_ws + 128;
    float* psig   = (float*)d_ws + 256;
    float* pcnt   = psig + KTOP * CHUNKS;

    topk_kernel<<<1, 256, 0, stream>>>(pred_logits, ws_idx, ws_sc);

    dim3 grid(CHUNKS, KTOP);
    mask_kernel<<<grid, 256, 0, stream>>>((const vfloat4*)pred_masks, ws_idx,
                                          (vfloat4*)out, psig, pcnt);

    final_kernel<<<1, 128, 0, stream>>>(ws_idx, ws_sc, psig, pcnt,
                                        labels, ids, out);
}